// Round 2
// baseline (611.599 us; speedup 1.0000x reference)
//
#include <hip/hip_runtime.h>

// VQ-VAE forward: N=131072 rows (D=64), K=512 codes.
// Outputs flat: [loss(1) | quantized_st(8388608, NCHW) | perplexity(1) | encodings(131072x512)]
//
// R2 changes vs R1 (theory: latency-bound; VGPR_Count=48 proved x[64] was not VGPR-resident):
//  - __launch_bounds__(256,3): VGPR cap ~170 so x[64] stays in registers (was spilling).
//  - K-split x2: each row-group (64 rows) scanned by TWO waves (256 codes each),
//    argmin combined in LDS with numpy's first-min tie rule. 1024 blocks -> 16 waves/CU.
//  - Epilogue (quantized write + loss) split by channel half between the two waves.

#define OFF_Q    1
#define OFF_PERP 8388609
#define OFF_ENC  8388610

__global__ __launch_bounds__(512) void vq_prep(const float* __restrict__ emb,
                                               float* __restrict__ Bk,
                                               unsigned* __restrict__ counts,
                                               unsigned long long* __restrict__ lossAcc) {
    int k = threadIdx.x;  // 512 threads, one per code
    const float4* e4 = reinterpret_cast<const float4*>(emb) + k * 16;
    float s = 0.f;
    #pragma unroll
    for (int i = 0; i < 16; ++i) {
        float4 v = e4[i];
        s += v.x * v.x + v.y * v.y + v.z * v.z + v.w * v.w;
    }
    Bk[k] = s;
    counts[k] = 0u;
    if (k == 0) *lossAcc = 0ull;
}

__global__ __launch_bounds__(256, 3) void vq_main(const float* __restrict__ in,
                                                  const float* __restrict__ emb,
                                                  const float* __restrict__ Bk,
                                                  unsigned* __restrict__ counts,
                                                  unsigned long long* __restrict__ lossAcc,
                                                  float* __restrict__ out) {
    const int tid  = (int)threadIdx.x;
    const int wv   = tid >> 6;          // 0..3
    const int lane = tid & 63;          // = w
    const int gib  = wv >> 1;           // row-group within block (0..1)
    const int half = wv & 1;            // K-half this wave scans
    const int g    = (int)blockIdx.x * 2 + gib;   // row-group 0..2047 = b*64+h
    const int bb = g >> 6;
    const int hh = g & 63;
    const size_t inBase = (size_t)bb * 262144 + (size_t)hh * 64 + (size_t)lane;

    __shared__ float sdLds[4][64];
    __shared__ int   skLds[4][64];

    // Load this lane's row: x[c] = inputs[b, c, h, w]; coalesced across lanes per c.
    float x[64];
    #pragma unroll
    for (int c = 0; c < 64; ++c) x[c] = in[inBase + (size_t)c * 4096];

    // ||x||^2 (4 partials for ILP)
    float a0 = 0.f, a1 = 0.f, a2 = 0.f, a3 = 0.f;
    #pragma unroll
    for (int c = 0; c < 64; c += 4) {
        a0 += x[c] * x[c];
        a1 += x[c + 1] * x[c + 1];
        a2 += x[c + 2] * x[c + 2];
        a3 += x[c + 3] * x[c + 3];
    }
    const float A = (a0 + a1) + (a2 + a3);

    // Encodings slab for group g: 32768 floats. This wave zero-fills its half (64KB),
    // paced one float2 store per k-iteration. Base is 8B-aligned.
    float2* enc2 = reinterpret_cast<float2*>(out + OFF_ENC + (size_t)g * 32768 + (size_t)half * 16384);
    const float2 z2 = make_float2(0.f, 0.f);

    float bestd = 3.4e38f;
    int bestk = half * 256;

    // Scan this wave's 256 codes: 2 per iteration + 1 paced zero-fill store.
    for (int kk = 0; kk < 128; ++kk) {
        enc2[kk * 64 + lane] = z2;

        #pragma unroll
        for (int u = 0; u < 2; ++u) {
            const int k = half * 256 + kk * 2 + u;
            const float* __restrict__ e = emb + k * 64;  // wave-uniform -> s_load
            float c0 = 0.f, c1 = 0.f, c2 = 0.f, c3 = 0.f;
            #pragma unroll
            for (int d = 0; d < 64; d += 4) {
                c0 += x[d]     * e[d];
                c1 += x[d + 1] * e[d + 1];
                c2 += x[d + 2] * e[d + 2];
                c3 += x[d + 3] * e[d + 3];
            }
            float dot  = (c0 + c1) + (c2 + c3);
            float dist = (A + Bk[k]) - 2.0f * dot;            // reference op order
            if (dist < bestd) { bestd = dist; bestk = k; }    // strict < = first-min
        }
    }

    // Combine the two halves' argmin (numpy first-min rule: tie -> lower index = half 0).
    sdLds[wv][lane] = bestd;
    skLds[wv][lane] = bestk;
    __syncthreads();   // also drains the zero-fill stores (vmcnt(0) before barrier)
    const int base = gib * 2;
    const float d0 = sdLds[base][lane];
    const float d1 = sdLds[base + 1][lane];
    const int   k0 = skLds[base][lane];
    const int   k1 = skLds[base + 1][lane];
    const int   kb = (d1 < d0) ? k1 : k0;

    // Epilogue split by channel half: this wave handles c in [half*32, half*32+32).
    const float* __restrict__ eq = emb + kb * 64;
    const int cbeg = half * 32;
    float l0 = 0.f, l1 = 0.f, l2 = 0.f, l3 = 0.f;
    #pragma unroll
    for (int c = 0; c < 32; c += 4) {
        const int cc = cbeg + c;
        float q0 = eq[cc], q1 = eq[cc + 1], q2 = eq[cc + 2], q3 = eq[cc + 3];
        float e0 = q0 - x[cc],     e1 = q1 - x[cc + 1];
        float e2 = q2 - x[cc + 2], e3 = q3 - x[cc + 3];
        l0 += e0 * e0; l1 += e1 * e1; l2 += e2 * e2; l3 += e3 * e3;
        out[OFF_Q + inBase + (size_t)cc * 4096]       = x[cc]     + e0;
        out[OFF_Q + inBase + (size_t)(cc + 1) * 4096] = x[cc + 1] + e1;
        out[OFF_Q + inBase + (size_t)(cc + 2) * 4096] = x[cc + 2] + e2;
        out[OFF_Q + inBase + (size_t)(cc + 3) * 4096] = x[cc + 3] + e3;
    }
    float lsum = (l0 + l1) + (l2 + l3);
    #pragma unroll
    for (int off = 32; off > 0; off >>= 1) lsum += __shfl_down(lsum, off);
    if (lane == 0) {
        unsigned long long fx = (unsigned long long)((double)lsum * 1048576.0);
        atomicAdd(lossAcc, fx);
    }

    // One-hot scatter + counts: half-0 wave only. Zero-fill of the whole slab is
    // complete (both waves drained stores at __syncthreads above).
    if (half == 0) {
        atomicAdd(&counts[kb], 1u);
        out[OFF_ENC + (size_t)g * 32768 + (size_t)lane * 512 + (size_t)kb] = 1.0f;
    }
}

__global__ __launch_bounds__(512) void vq_fin(const unsigned* __restrict__ counts,
                                              const unsigned long long* __restrict__ lossAcc,
                                              float* __restrict__ out) {
    __shared__ float red[512];
    int k = threadIdx.x;
    float p = (float)counts[k] * (1.0f / 131072.0f);  // exact: count * 2^-17
    red[k] = p * logf(p + 1e-10f);
    __syncthreads();
    for (int s = 256; s > 0; s >>= 1) {
        if (k < s) red[k] += red[k + s];
        __syncthreads();
    }
    if (k == 0) {
        out[OFF_PERP] = expf(-red[0]);
        double m = ((double)(*lossAcc) / 1048576.0) / 8388608.0;
        float mf = (float)m;
        out[0] = mf + 0.25f * mf;  // q_latent + 0.25 * e_latent (identical values)
    }
}

extern "C" void kernel_launch(void* const* d_in, const int* in_sizes, int n_in,
                              void* d_out, int out_size, void* d_ws, size_t ws_size,
                              hipStream_t stream) {
    const float* in  = (const float*)d_in[0];
    // d_in[1] = labels (unused by the reference forward)
    const float* emb = (const float*)d_in[2];
    float* out = (float*)d_out;

    float* Bk                    = (float*)d_ws;                              // 512 f32
    unsigned* counts             = (unsigned*)((char*)d_ws + 2048);           // 512 u32
    unsigned long long* lossAcc  = (unsigned long long*)((char*)d_ws + 4096); // 1 u64

    vq_prep<<<1, 512, 0, stream>>>(emb, Bk, counts, lossAcc);
    vq_main<<<1024, 256, 0, stream>>>(in, emb, Bk, counts, lossAcc, out);
    vq_fin<<<1, 512, 0, stream>>>(counts, lossAcc, out);
}

// Round 3
// 197.141 us; speedup vs baseline: 3.1023x; 3.1023x over previous
//
#include <hip/hip_runtime.h>

// VQ-VAE forward: N=131072 rows (D=64), K=512 codes.
// Outputs flat: [loss(1) | quantized_st(8388608, NCHW) | perplexity(1) | encodings(131072x512)]
//
// R3 theory (from R1/R2 counters):
//  - R1/R2 VGPR=48/52 -> x[] was re-fetched from global inside the k-loop (~8GB via L2 = the
//    268us). Fix: asm "+v" pins make x opaque VGPR defs (cannot be rematerialized).
//  - R2 SGPR 112->32 -> k became "divergent" (tid-derived) so embedding fell off the s_load
//    path. Fix: derive the K-half via __builtin_amdgcn_readfirstlane -> provably uniform.
//  - 2 rows/lane register blocking: 128 FMAs per e-row; 1024 blocks x 2 waves = 2 waves/SIMD.
//  - Encodings zero-fill paced: one float2 wave-store per code-iter = 128KB/wave over 256 iters.

#define OFF_Q    1
#define OFF_PERP 8388609
#define OFF_ENC  8388610

__global__ __launch_bounds__(512) void vq_prep(const float* __restrict__ emb,
                                               float* __restrict__ Bk,
                                               unsigned* __restrict__ counts,
                                               unsigned long long* __restrict__ lossAcc) {
    int k = threadIdx.x;  // 512 threads, one per code
    const float4* e4 = reinterpret_cast<const float4*>(emb) + k * 16;
    float s = 0.f;
    #pragma unroll
    for (int i = 0; i < 16; ++i) {
        float4 v = e4[i];
        s += v.x * v.x + v.y * v.y + v.z * v.z + v.w * v.w;
    }
    Bk[k] = s;
    counts[k] = 0u;
    if (k == 0) *lossAcc = 0ull;
}

__global__ __launch_bounds__(128, 2) void vq_main(const float* __restrict__ in,
                                                  const float* __restrict__ emb,
                                                  const float* __restrict__ Bk,
                                                  unsigned* __restrict__ counts,
                                                  unsigned long long* __restrict__ lossAcc,
                                                  float* __restrict__ out) {
    const int lane = (int)threadIdx.x & 63;
    const int h    = __builtin_amdgcn_readfirstlane(((int)threadIdx.x >> 6) & 1); // uniform K-half
    const int g    = (int)blockIdx.x;              // row-group: rows g*128 .. g*128+127
    const int bb   = g >> 5;                       // 32 groups per batch image
    const int sp0  = (g & 31) * 128;               // spatial offset of row 0 of group

    __shared__ float sd[2][2][64];                 // [k-half][row-slot r][lane]
    __shared__ int   sk[2][2][64];

    // ---- load this lane's 2 rows (r=0: row lane, r=1: row 64+lane) ----
    // x[r*64+c] = in[bb, c, sp0 + r*64 + lane]
    const size_t inBase = (size_t)bb * 262144 + (size_t)sp0 + (size_t)lane;
    float x[128];
    #pragma unroll
    for (int r = 0; r < 2; ++r)
        #pragma unroll
        for (int c = 0; c < 64; ++c)
            x[r * 64 + c] = in[inBase + (size_t)r * 64 + (size_t)c * 4096];

    // Pin every x value in a VGPR: opaque defs, compiler cannot re-load from global.
    #pragma unroll
    for (int i = 0; i < 128; ++i) asm volatile("" : "+v"(x[i]));

    // ||x||^2 per row
    float A[2];
    #pragma unroll
    for (int r = 0; r < 2; ++r) {
        float a0 = 0.f, a1 = 0.f, a2 = 0.f, a3 = 0.f;
        #pragma unroll
        for (int c = 0; c < 64; c += 4) {
            a0 += x[r * 64 + c]     * x[r * 64 + c];
            a1 += x[r * 64 + c + 1] * x[r * 64 + c + 1];
            a2 += x[r * 64 + c + 2] * x[r * 64 + c + 2];
            a3 += x[r * 64 + c + 3] * x[r * 64 + c + 3];
        }
        A[r] = (a0 + a1) + (a2 + a3);
    }

    // Encodings zero-fill region for this wave: rows [h*64, h*64+64) of the group slab,
    // 32768 floats, 8B-aligned. One float2 wave-store per code iteration.
    float2* enc2 = reinterpret_cast<float2*>(out + OFF_ENC + (size_t)g * 65536 + (size_t)h * 32768);
    const float2 z2 = make_float2(0.f, 0.f);

    const int kbase = h * 256;
    float bd0 = 3.4e38f, bd1 = 3.4e38f;
    int   bk0 = kbase,   bk1 = kbase;

    for (int kk = 0; kk < 256; ++kk) {
        enc2[kk * 64 + lane] = z2;   // paced zero-fill (512B/wave/iter)

        const int k = kbase + kk;    // uniform -> emb row via s_load
        const float* __restrict__ e = emb + (size_t)k * 64;
        const float bkk = Bk[k];

        float a0 = 0.f, a1 = 0.f, a2 = 0.f, a3 = 0.f;
        float b0 = 0.f, b1 = 0.f, b2 = 0.f, b3 = 0.f;
        #pragma unroll
        for (int d = 0; d < 64; d += 4) {
            float e0 = e[d], e1 = e[d + 1], e2 = e[d + 2], e3 = e[d + 3];
            a0 += x[d]      * e0;  a1 += x[d + 1]  * e1;
            a2 += x[d + 2]  * e2;  a3 += x[d + 3]  * e3;
            b0 += x[64 + d]     * e0;  b1 += x[64 + d + 1] * e1;
            b2 += x[64 + d + 2] * e2;  b3 += x[64 + d + 3] * e3;
        }
        float dot0 = (a0 + a1) + (a2 + a3);
        float dot1 = (b0 + b1) + (b2 + b3);
        float di0 = (A[0] + bkk) - 2.0f * dot0;   // reference op order
        float di1 = (A[1] + bkk) - 2.0f * dot1;
        if (di0 < bd0) { bd0 = di0; bk0 = k; }    // strict < = first-min (numpy tie rule)
        if (di1 < bd1) { bd1 = di1; bk1 = k; }
    }

    sd[h][0][lane] = bd0;  sk[h][0][lane] = bk0;
    sd[h][1][lane] = bd1;  sk[h][1][lane] = bk1;
    __syncthreads();   // drains zero-fill stores (vmcnt(0) before s_barrier) + shares argmins

    // Combine halves per row (tie -> lower k = half 0).
    int kbr[2];
    #pragma unroll
    for (int r = 0; r < 2; ++r) {
        float d0 = sd[0][r][lane], d1 = sd[1][r][lane];
        kbr[r] = (d1 < d0) ? sk[1][r][lane] : sk[0][r][lane];
    }

    // One row per (wave, lane): row r=h, lane. Count + one-hot scatter (region zero-filled
    // by this same wave, drained at the barrier above).
    const int kown = (h == 0) ? kbr[0] : kbr[1];
    atomicAdd(&counts[kown], 1u);
    out[OFF_ENC + (size_t)g * 65536 + (size_t)(h * 64 + lane) * 512 + (size_t)kown] = 1.0f;

    // Epilogue: this wave handles channels [h*32, h*32+32) for BOTH its rows.
    // (uniform branch keeps all x[] indices compile-time constant -> no scratch)
    float l0 = 0.f, l1 = 0.f, l2 = 0.f, l3 = 0.f;
    #pragma unroll
    for (int r = 0; r < 2; ++r) {
        const float* __restrict__ eq = emb + (size_t)kbr[r] * 64;
        const size_t qBase = OFF_Q + inBase + (size_t)r * 64;
        if (h == 0) {
            #pragma unroll
            for (int c = 0; c < 32; c += 4) {
                float q0 = eq[c], q1 = eq[c + 1], q2 = eq[c + 2], q3 = eq[c + 3];
                float e0 = q0 - x[r * 64 + c],     e1 = q1 - x[r * 64 + c + 1];
                float e2 = q2 - x[r * 64 + c + 2], e3 = q3 - x[r * 64 + c + 3];
                l0 += e0 * e0; l1 += e1 * e1; l2 += e2 * e2; l3 += e3 * e3;
                out[qBase + (size_t)c * 4096]       = x[r * 64 + c]     + e0;
                out[qBase + (size_t)(c + 1) * 4096] = x[r * 64 + c + 1] + e1;
                out[qBase + (size_t)(c + 2) * 4096] = x[r * 64 + c + 2] + e2;
                out[qBase + (size_t)(c + 3) * 4096] = x[r * 64 + c + 3] + e3;
            }
        } else {
            #pragma unroll
            for (int c = 32; c < 64; c += 4) {
                float q0 = eq[c], q1 = eq[c + 1], q2 = eq[c + 2], q3 = eq[c + 3];
                float e0 = q0 - x[r * 64 + c],     e1 = q1 - x[r * 64 + c + 1];
                float e2 = q2 - x[r * 64 + c + 2], e3 = q3 - x[r * 64 + c + 3];
                l0 += e0 * e0; l1 += e1 * e1; l2 += e2 * e2; l3 += e3 * e3;
                out[qBase + (size_t)c * 4096]       = x[r * 64 + c]     + e0;
                out[qBase + (size_t)(c + 1) * 4096] = x[r * 64 + c + 1] + e1;
                out[qBase + (size_t)(c + 2) * 4096] = x[r * 64 + c + 2] + e2;
                out[qBase + (size_t)(c + 3) * 4096] = x[r * 64 + c + 3] + e3;
            }
        }
    }
    float lsum = (l0 + l1) + (l2 + l3);
    #pragma unroll
    for (int off = 32; off > 0; off >>= 1) lsum += __shfl_down(lsum, off);
    if (lane == 0) {
        unsigned long long fx = (unsigned long long)((double)lsum * 1048576.0);
        atomicAdd(lossAcc, fx);
    }
}

__global__ __launch_bounds__(512) void vq_fin(const unsigned* __restrict__ counts,
                                              const unsigned long long* __restrict__ lossAcc,
                                              float* __restrict__ out) {
    __shared__ float red[512];
    int k = threadIdx.x;
    float p = (float)counts[k] * (1.0f / 131072.0f);  // exact: count * 2^-17
    red[k] = p * logf(p + 1e-10f);
    __syncthreads();
    for (int s = 256; s > 0; s >>= 1) {
        if (k < s) red[k] += red[k + s];
        __syncthreads();
    }
    if (k == 0) {
        out[OFF_PERP] = expf(-red[0]);
        double m = ((double)(*lossAcc) / 1048576.0) / 8388608.0;
        float mf = (float)m;
        out[0] = mf + 0.25f * mf;  // q_latent + 0.25 * e_latent (identical values)
    }
}

extern "C" void kernel_launch(void* const* d_in, const int* in_sizes, int n_in,
                              void* d_out, int out_size, void* d_ws, size_t ws_size,
                              hipStream_t stream) {
    const float* in  = (const float*)d_in[0];
    // d_in[1] = labels (unused by the reference forward)
    const float* emb = (const float*)d_in[2];
    float* out = (float*)d_out;

    float* Bk                    = (float*)d_ws;                              // 512 f32
    unsigned* counts             = (unsigned*)((char*)d_ws + 2048);           // 512 u32
    unsigned long long* lossAcc  = (unsigned long long*)((char*)d_ws + 4096); // 1 u64

    vq_prep<<<1, 512, 0, stream>>>(emb, Bk, counts, lossAcc);
    vq_main<<<1024, 128, 0, stream>>>(in, emb, Bk, counts, lossAcc, out);
    vq_fin<<<1, 512, 0, stream>>>(counts, lossAcc, out);
}